// Round 1
// baseline (474.615 us; speedup 1.0000x reference)
//
#include <hip/hip_runtime.h>
#include <math.h>

#define CH   64
#define NTOT 4096
#define NB   4

// ---------------------------------------------------------------------------
// Kernel 1: QKV projection.  x:(B,C,N) f32 -> k,q,v:(B,C,N) f32
// grid = B * (N/64) = 256 blocks, 256 threads
// ---------------------------------------------------------------------------
__global__ __launch_bounds__(256) void qkv_proj(
    const float* __restrict__ x,
    const float* __restrict__ Wk, const float* __restrict__ Wq,
    const float* __restrict__ Wv,
    float* __restrict__ k, float* __restrict__ q, float* __restrict__ v)
{
    __shared__ __align__(16) float xs [64][68];
    __shared__ __align__(16) float wkT[64][68];   // [c][o]
    __shared__ __align__(16) float wqT[64][68];
    __shared__ __align__(16) float wvT[64][68];

    const int tid = threadIdx.x;
    const int b  = blockIdx.x >> 6;
    const int n0 = (blockIdx.x & 63) * 64;
    const float* xb = x + (size_t)b * CH * NTOT;

    for (int i = tid; i < 64 * 64; i += 256) {
        int c = i >> 6, n = i & 63;
        xs[c][n] = xb[(size_t)c * NTOT + n0 + n];
    }
    for (int i = tid; i < 64 * 64; i += 256) {
        int o = i >> 6, c = i & 63;
        wkT[c][o] = Wk[i];
        wqT[c][o] = Wq[i];
        wvT[c][o] = Wv[i];
    }
    __syncthreads();

    const int to = tid >> 4, tn = tid & 15;
    const int ob = to * 4, nb = tn * 4;
    float ak[4][4] = {}, aq[4][4] = {}, av[4][4] = {};

    for (int c = 0; c < 64; ++c) {
        float4 xv = *(const float4*)&xs [c][nb];
        float4 k4 = *(const float4*)&wkT[c][ob];
        float4 q4 = *(const float4*)&wqT[c][ob];
        float4 v4 = *(const float4*)&wvT[c][ob];
        float xa[4] = {xv.x, xv.y, xv.z, xv.w};
        float ka[4] = {k4.x, k4.y, k4.z, k4.w};
        float qa[4] = {q4.x, q4.y, q4.z, q4.w};
        float va[4] = {v4.x, v4.y, v4.z, v4.w};
        #pragma unroll
        for (int i = 0; i < 4; ++i)
            #pragma unroll
            for (int j = 0; j < 4; ++j) {
                ak[i][j] += ka[i] * xa[j];
                aq[i][j] += qa[i] * xa[j];
                av[i][j] += va[i] * xa[j];
            }
    }

    #pragma unroll
    for (int i = 0; i < 4; ++i) {
        size_t base = ((size_t)b * CH + ob + i) * NTOT + n0 + nb;
        *(float4*)&k[base] = make_float4(ak[i][0], ak[i][1], ak[i][2], ak[i][3]);
        *(float4*)&q[base] = make_float4(aq[i][0], aq[i][1], aq[i][2], aq[i][3]);
        *(float4*)&v[base] = make_float4(av[i][0], av[i][1], av[i][2], av[i][3]);
    }
}

// ---------------------------------------------------------------------------
// Kernel 2: flash attention.
//   scores[n,m] = sum_c k[c,n]*q[c,m]; p = softmax_m; att[c,n] = sum_m p*v[c,m]
// grid = B * (N/64) = 256 blocks, 256 threads; QB=64 queries, MB=64 keys/tile
// ---------------------------------------------------------------------------
__global__ __launch_bounds__(256) void attn(
    const float* __restrict__ k, const float* __restrict__ q,
    const float* __restrict__ v, float* __restrict__ att)
{
    __shared__ __align__(16) float kq[64][68];   // [c][n]   queries (k cols)
    __shared__ __align__(16) float qs[64][68];   // [c][m]   keys    (q cols)
    __shared__ __align__(16) float vT[64][68];   // [m][c]   values transposed
    __shared__ __align__(16) float pT[64][68];   // [m][n]   scores/probs^T
    __shared__ __align__(16) float mrun[64], lrun[64], fscale[64];

    const int tid = threadIdx.x;
    const int b  = blockIdx.x >> 6;
    const int n0 = (blockIdx.x & 63) * 64;
    const float* kb = k + (size_t)b * CH * NTOT;
    const float* qb = q + (size_t)b * CH * NTOT;
    const float* vb = v + (size_t)b * CH * NTOT;

    for (int i = tid; i < 64 * 64; i += 256) {
        int c = i >> 6, n = i & 63;
        kq[c][n] = kb[(size_t)c * NTOT + n0 + n];
    }
    if (tid < 64) { mrun[tid] = -1e30f; lrun[tid] = 0.0f; }

    const int tc = tid >> 4, tn = tid & 15;
    const int cb = tc * 4, nbk = tn * 4;
    float acc[4][4] = {};
    __syncthreads();

    for (int m0 = 0; m0 < NTOT; m0 += 64) {
        // ---- stage key / value tiles ----
        for (int i = tid; i < 64 * 64; i += 256) {
            int c = i >> 6, m = i & 63;
            size_t g = (size_t)c * NTOT + m0 + m;
            qs[c][m] = qb[g];
            vT[m][c] = vb[g];
        }
        __syncthreads();

        // ---- S^T tile: pT[m][n] = sum_c qs[c][m] * kq[c][n] ----
        {
            const int mb  = (tid >> 4) * 4;
            const int nb2 = (tid & 15) * 4;
            float s[4][4] = {};
            for (int c = 0; c < 64; ++c) {
                float4 q4 = *(const float4*)&qs[c][mb];
                float4 k4 = *(const float4*)&kq[c][nb2];
                float qa[4] = {q4.x, q4.y, q4.z, q4.w};
                float ka[4] = {k4.x, k4.y, k4.z, k4.w};
                #pragma unroll
                for (int i = 0; i < 4; ++i)
                    #pragma unroll
                    for (int j = 0; j < 4; ++j)
                        s[i][j] += qa[i] * ka[j];
            }
            #pragma unroll
            for (int i = 0; i < 4; ++i)
                *(float4*)&pT[mb + i][nb2] =
                    make_float4(s[i][0], s[i][1], s[i][2], s[i][3]);
        }
        __syncthreads();

        // ---- online softmax over m (columns of pT) ----
        {
            const int w = tid >> 6, l = tid & 63;
            const int n  = 16 * w + (l >> 2);   // each n handled by 4 lanes
            const int s0 = l & 3;
            float mx = -1e30f;
            for (int m = s0; m < 64; m += 4) mx = fmaxf(mx, pT[m][n]);
            mx = fmaxf(mx, __shfl_xor(mx, 1));
            mx = fmaxf(mx, __shfl_xor(mx, 2));
            float mold = mrun[n];
            float mnew = fmaxf(mold, mx);
            float sum = 0.0f;
            for (int m = s0; m < 64; m += 4) {
                float p = __expf(pT[m][n] - mnew);
                pT[m][n] = p;
                sum += p;
            }
            sum += __shfl_xor(sum, 1);
            sum += __shfl_xor(sum, 2);
            if (s0 == 0) {
                float f = __expf(mold - mnew);
                fscale[n] = f;
                lrun[n] = lrun[n] * f + sum;
                mrun[n] = mnew;
            }
        }
        __syncthreads();

        // ---- rescale accumulator, accumulate PV ----
        {
            float4 f4 = *(const float4*)&fscale[nbk];
            float fs[4] = {f4.x, f4.y, f4.z, f4.w};
            #pragma unroll
            for (int i = 0; i < 4; ++i)
                #pragma unroll
                for (int j = 0; j < 4; ++j) acc[i][j] *= fs[j];
            #pragma unroll 4
            for (int m = 0; m < 64; ++m) {
                float4 p4 = *(const float4*)&pT[m][nbk];
                float4 v4 = *(const float4*)&vT[m][cb];
                float pa[4] = {p4.x, p4.y, p4.z, p4.w};
                float va[4] = {v4.x, v4.y, v4.z, v4.w};
                #pragma unroll
                for (int i = 0; i < 4; ++i)
                    #pragma unroll
                    for (int j = 0; j < 4; ++j)
                        acc[i][j] += va[i] * pa[j];
            }
        }
        __syncthreads();   // before next tile overwrites qs/vT/pT
    }

    // ---- finalize: att[c][n] = acc / lrun[n] ----
    float4 l4 = *(const float4*)&lrun[nbk];
    float rl[4] = {1.0f / l4.x, 1.0f / l4.y, 1.0f / l4.z, 1.0f / l4.w};
    #pragma unroll
    for (int i = 0; i < 4; ++i) {
        size_t base = ((size_t)b * CH + cb + i) * NTOT + n0 + nbk;
        *(float4*)&att[base] = make_float4(acc[i][0] * rl[0], acc[i][1] * rl[1],
                                           acc[i][2] * rl[2], acc[i][3] * rl[3]);
    }
}

// ---------------------------------------------------------------------------
// Kernel 3: output projection + BN(inference) + ReLU + residual
// ---------------------------------------------------------------------------
__global__ __launch_bounds__(256) void out_proj(
    const float* __restrict__ att, const float* __restrict__ W2,
    const float* __restrict__ gamma, const float* __restrict__ beta,
    const float* __restrict__ rmean, const float* __restrict__ rvar,
    const float* __restrict__ x, float* __restrict__ out)
{
    __shared__ __align__(16) float as [64][68];
    __shared__ __align__(16) float w2T[64][68];

    const int tid = threadIdx.x;
    const int b  = blockIdx.x >> 6;
    const int n0 = (blockIdx.x & 63) * 64;
    const float* ab = att + (size_t)b * CH * NTOT;

    for (int i = tid; i < 64 * 64; i += 256) {
        int c = i >> 6, n = i & 63;
        as[c][n] = ab[(size_t)c * NTOT + n0 + n];
    }
    for (int i = tid; i < 64 * 64; i += 256) {
        int o = i >> 6, c = i & 63;
        w2T[c][o] = W2[i];
    }
    __syncthreads();

    const int to = tid >> 4, tn = tid & 15;
    const int ob = to * 4, nb = tn * 4;
    float ay[4][4] = {};

    for (int c = 0; c < 64; ++c) {
        float4 a4 = *(const float4*)&as [c][nb];
        float4 w4 = *(const float4*)&w2T[c][ob];
        float aa[4] = {a4.x, a4.y, a4.z, a4.w};
        float wa[4] = {w4.x, w4.y, w4.z, w4.w};
        #pragma unroll
        for (int i = 0; i < 4; ++i)
            #pragma unroll
            for (int j = 0; j < 4; ++j)
                ay[i][j] += wa[i] * aa[j];
    }

    #pragma unroll
    for (int i = 0; i < 4; ++i) {
        int o = ob + i;
        float inv  = gamma[o] * rsqrtf(rvar[o] + 1e-5f);
        float bias = beta[o] - rmean[o] * inv;
        size_t base = ((size_t)b * CH + o) * NTOT + n0 + nb;
        float4 x4 = *(const float4*)&x[base];
        float xa[4] = {x4.x, x4.y, x4.z, x4.w};
        float r[4];
        #pragma unroll
        for (int j = 0; j < 4; ++j)
            r[j] = fmaxf(ay[i][j] * inv + bias, 0.0f) + xa[j];
        *(float4*)&out[base] = make_float4(r[0], r[1], r[2], r[3]);
    }
}

// ---------------------------------------------------------------------------
extern "C" void kernel_launch(void* const* d_in, const int* in_sizes, int n_in,
                              void* d_out, int out_size, void* d_ws, size_t ws_size,
                              hipStream_t stream)
{
    const float* x     = (const float*)d_in[0];
    const float* Wk    = (const float*)d_in[1];
    const float* Wq    = (const float*)d_in[2];
    const float* Wv    = (const float*)d_in[3];
    const float* W2    = (const float*)d_in[4];
    const float* gamma = (const float*)d_in[5];
    const float* beta  = (const float*)d_in[6];
    const float* rmean = (const float*)d_in[7];
    const float* rvar  = (const float*)d_in[8];
    float* out = (float*)d_out;

    const size_t plane = (size_t)NB * CH * NTOT;   // 1M floats = 4 MB
    float* k   = (float*)d_ws;
    float* q   = k + plane;
    float* v   = q + plane;
    float* att = v + plane;

    qkv_proj<<<dim3(NB * (NTOT / 64)), dim3(256), 0, stream>>>(x, Wk, Wq, Wv, k, q, v);
    attn    <<<dim3(NB * (NTOT / 64)), dim3(256), 0, stream>>>(k, q, v, att);
    out_proj<<<dim3(NB * (NTOT / 64)), dim3(256), 0, stream>>>(att, W2, gamma, beta,
                                                               rmean, rvar, x, out);
}

// Round 3
// 116.219 us; speedup vs baseline: 4.0838x; 4.0838x over previous
//
#include <hip/hip_runtime.h>
#include <math.h>

#define CH   64
#define NTOT 4096
#define NB   4

typedef short  short4v  __attribute__((ext_vector_type(4)));
typedef short  short8v  __attribute__((ext_vector_type(8)));
typedef float  floatx4  __attribute__((ext_vector_type(4)));

static __device__ __forceinline__ short f2bf(float f) {
    union { float f; unsigned int u; } v; v.f = f;
    unsigned int r = v.u + 0x7FFFu + ((v.u >> 16) & 1u);   // RNE
    return (short)(r >> 16);
}

// ---------------------------------------------------------------------------
// Kernel 1: QKV projection (fp32 compute) -> bf16 outputs
//   kT, qT : (B, N, C)  bf16   (pos-major, for MFMA fragment reads)
//   v      : (B, C, N)  bf16
// ---------------------------------------------------------------------------
__global__ __launch_bounds__(256) void qkv_proj(
    const float* __restrict__ x,
    const float* __restrict__ Wk, const float* __restrict__ Wq,
    const float* __restrict__ Wv,
    short* __restrict__ kT, short* __restrict__ qT, short* __restrict__ vg)
{
    __shared__ __align__(16) float xs [64][68];
    __shared__ __align__(16) float wkT[64][68];
    __shared__ __align__(16) float wqT[64][68];
    __shared__ __align__(16) float wvT[64][68];

    const int tid = threadIdx.x;
    const int b  = blockIdx.x >> 6;
    const int n0 = (blockIdx.x & 63) * 64;
    const float* xb = x + (size_t)b * CH * NTOT;

    for (int i = tid; i < 64 * 64; i += 256) {
        int c = i >> 6, n = i & 63;
        xs[c][n] = xb[(size_t)c * NTOT + n0 + n];
    }
    for (int i = tid; i < 64 * 64; i += 256) {
        int o = i >> 6, c = i & 63;
        wkT[c][o] = Wk[i];
        wqT[c][o] = Wq[i];
        wvT[c][o] = Wv[i];
    }
    __syncthreads();

    const int to = tid >> 4, tn = tid & 15;
    const int ob = to * 4, nb = tn * 4;
    float ak[4][4] = {}, aq[4][4] = {}, av[4][4] = {};

    for (int c = 0; c < 64; ++c) {
        float4 xv = *(const float4*)&xs [c][nb];
        float4 k4 = *(const float4*)&wkT[c][ob];
        float4 q4 = *(const float4*)&wqT[c][ob];
        float4 v4 = *(const float4*)&wvT[c][ob];
        float xa[4] = {xv.x, xv.y, xv.z, xv.w};
        float ka[4] = {k4.x, k4.y, k4.z, k4.w};
        float qa[4] = {q4.x, q4.y, q4.z, q4.w};
        float va[4] = {v4.x, v4.y, v4.z, v4.w};
        #pragma unroll
        for (int i = 0; i < 4; ++i)
            #pragma unroll
            for (int j = 0; j < 4; ++j) {
                ak[i][j] += ka[i] * xa[j];
                aq[i][j] += qa[i] * xa[j];
                av[i][j] += va[i] * xa[j];
            }
    }

    #pragma unroll
    for (int j = 0; j < 4; ++j) {
        size_t row = (size_t)(b << 12) + n0 + nb + j;
        short4v kk = { f2bf(ak[0][j]), f2bf(ak[1][j]), f2bf(ak[2][j]), f2bf(ak[3][j]) };
        short4v qq = { f2bf(aq[0][j]), f2bf(aq[1][j]), f2bf(aq[2][j]), f2bf(aq[3][j]) };
        *(short4v*)&kT[row * 64 + ob] = kk;
        *(short4v*)&qT[row * 64 + ob] = qq;
    }
    #pragma unroll
    for (int i = 0; i < 4; ++i) {
        short4v vv = { f2bf(av[i][0]), f2bf(av[i][1]), f2bf(av[i][2]), f2bf(av[i][3]) };
        *(short4v*)&vg[(((size_t)(b << 6) + ob + i) << 12) + n0 + nb] = vv;
    }
}

// ---------------------------------------------------------------------------
// Kernel 2: fused flash attention + output proj + BN + ReLU + residual (MFMA)
// block = 64 queries, 4 waves x 16 query rows; loop over 64-key tiles
// ---------------------------------------------------------------------------
__global__ __launch_bounds__(256) void fused_attn(
    const short* __restrict__ kT, const short* __restrict__ qT,
    const short* __restrict__ vg,
    const float* __restrict__ W2,
    const float* __restrict__ gamma, const float* __restrict__ beta,
    const float* __restrict__ rmean, const float* __restrict__ rvar,
    const float* __restrict__ x, float* __restrict__ out)
{
    __shared__ __align__(16) short kTs[64][72];   // [n][c]
    __shared__ __align__(16) short qTs[64][72];   // [m][c]; later reused: W2 bf16 [o][c]
    __shared__ __align__(16) short vs [64][72];   // [c][m]
    __shared__ __align__(16) short Ps [4][16][72];// per-wave P [n][m]; later att [n][c]
    __shared__ float bn_inv[64], bn_bias[64];

    const int tid = threadIdx.x;
    const int w  = tid >> 6;
    const int l  = tid & 63;
    const int g  = l >> 4;
    const int ln = l & 15;
    const int bsrc = (ln >> 2) << 4;   // lane holding stats for query ln (any lane of group ln>>2)

    const int bid = blockIdx.x;
    const int xcd = bid & 7, idx = bid >> 3;
    const int b    = xcd >> 1;
    const int nblk = ((xcd & 1) << 5) | idx;
    const int n0   = nblk << 6;

    const short* kTb = kT + ((size_t)(b << 12) + n0) * 64;
    const short* qTb = qT + ((size_t)b << 12) * 64;
    const short* vb  = vg + ((size_t)(b << 6) << 12);

    for (int i = tid; i < 512; i += 256) {
        int r = i >> 3, c8 = (i & 7) << 3;
        *(short8v*)&kTs[r][c8] = *(const short8v*)&kTb[r * 64 + c8];
    }
    if (tid < 64) {
        float inv = gamma[tid] * rsqrtf(rvar[tid] + 1e-5f);
        bn_inv[tid]  = inv;
        bn_bias[tid] = beta[tid] - rmean[tid] * inv;
    }
    __syncthreads();

    short8v aS0 = *(const short8v*)&kTs[(w << 4) + ln][(g << 3)];
    short8v aS1 = *(const short8v*)&kTs[(w << 4) + ln][32 + (g << 3)];

    float mrun[4] = {-1e30f, -1e30f, -1e30f, -1e30f};
    float lrun[4] = {0.f, 0.f, 0.f, 0.f};
    floatx4 acc_o[4];
    #pragma unroll
    for (int ct = 0; ct < 4; ++ct) acc_o[ct] = (floatx4){0.f, 0.f, 0.f, 0.f};

    short8v pf[4];
    {
        int i0 = tid, i1 = tid + 256;
        pf[0] = *(const short8v*)&qTb[(size_t)(i0 >> 3) * 64 + ((i0 & 7) << 3)];
        pf[1] = *(const short8v*)&qTb[(size_t)(i1 >> 3) * 64 + ((i1 & 7) << 3)];
        pf[2] = *(const short8v*)&vb[(size_t)(i0 >> 3) * 4096 + ((i0 & 7) << 3)];
        pf[3] = *(const short8v*)&vb[(size_t)(i1 >> 3) * 4096 + ((i1 & 7) << 3)];
    }

    for (int t = 0; t < 64; ++t) {
        __syncthreads();                       // previous tile's compute done
        {
            int i0 = tid, i1 = tid + 256;
            *(short8v*)&qTs[i0 >> 3][(i0 & 7) << 3] = pf[0];
            *(short8v*)&qTs[i1 >> 3][(i1 & 7) << 3] = pf[1];
            *(short8v*)&vs [i0 >> 3][(i0 & 7) << 3] = pf[2];
            *(short8v*)&vs [i1 >> 3][(i1 & 7) << 3] = pf[3];
        }
        __syncthreads();                       // tile ready
        if (t < 63) {
            int m1 = (t + 1) << 6;
            int i0 = tid, i1 = tid + 256;
            pf[0] = *(const short8v*)&qTb[(size_t)(m1 + (i0 >> 3)) * 64 + ((i0 & 7) << 3)];
            pf[1] = *(const short8v*)&qTb[(size_t)(m1 + (i1 >> 3)) * 64 + ((i1 & 7) << 3)];
            pf[2] = *(const short8v*)&vb[(size_t)(i0 >> 3) * 4096 + m1 + ((i0 & 7) << 3)];
            pf[3] = *(const short8v*)&vb[(size_t)(i1 >> 3) * 4096 + m1 + ((i1 & 7) << 3)];
        }

        // ---- S tile: D[n16][m64] = sum_c kT[n][c] * q[c][m] ----
        floatx4 sacc[4];
        #pragma unroll
        for (int mt = 0; mt < 4; ++mt) {
            short8v b0 = *(const short8v*)&qTs[(mt << 4) + ln][(g << 3)];
            short8v b1 = *(const short8v*)&qTs[(mt << 4) + ln][32 + (g << 3)];
            floatx4 acc = (floatx4){0.f, 0.f, 0.f, 0.f};
            acc = __builtin_amdgcn_mfma_f32_16x16x32_bf16(aS0, b0, acc, 0, 0, 0);
            acc = __builtin_amdgcn_mfma_f32_16x16x32_bf16(aS1, b1, acc, 0, 0, 0);
            sacc[mt] = acc;
        }

        // ---- online softmax over m (lane holds rows 4g+r, col ln per sub-tile) ----
        float fs[4];
        #pragma unroll
        for (int r = 0; r < 4; ++r) {
            float mx = fmaxf(fmaxf(sacc[0][r], sacc[1][r]), fmaxf(sacc[2][r], sacc[3][r]));
            mx = fmaxf(mx, __shfl_xor(mx, 1));
            mx = fmaxf(mx, __shfl_xor(mx, 2));
            mx = fmaxf(mx, __shfl_xor(mx, 4));
            mx = fmaxf(mx, __shfl_xor(mx, 8));
            float mnew = fmaxf(mrun[r], mx);
            fs[r] = __expf(mrun[r] - mnew);
            mrun[r] = mnew;
            float s = 0.f;
            #pragma unroll
            for (int mt = 0; mt < 4; ++mt) {
                float p = __expf(sacc[mt][r] - mnew);
                s += p;
                Ps[w][(g << 2) + r][(mt << 4) + ln] = f2bf(p);
            }
            s += __shfl_xor(s, 1);
            s += __shfl_xor(s, 2);
            s += __shfl_xor(s, 4);
            s += __shfl_xor(s, 8);
            lrun[r] = lrun[r] * fs[r] + s;
        }

        // broadcast fs(query=ln) via register shuffles (no LDS)
        {
            float f0 = __shfl(fs[0], bsrc);
            float f1 = __shfl(fs[1], bsrc);
            float f2 = __shfl(fs[2], bsrc);
            float f3 = __shfl(fs[3], bsrc);
            float fsn = (ln & 2) ? ((ln & 1) ? f3 : f2) : ((ln & 1) ? f1 : f0);
            #pragma unroll
            for (int ct = 0; ct < 4; ++ct) {
                acc_o[ct][0] *= fsn; acc_o[ct][1] *= fsn;
                acc_o[ct][2] *= fsn; acc_o[ct][3] *= fsn;
            }
        }

        __syncthreads();   // Ps writes visible/ordered before PV fragment reads

        // ---- PV: D2[c64][n16] += v[c][m] * P^T[m][n] ----
        short8v bp0 = *(const short8v*)&Ps[w][ln][(g << 3)];
        short8v bp1 = *(const short8v*)&Ps[w][ln][32 + (g << 3)];
        #pragma unroll
        for (int ct = 0; ct < 4; ++ct) {
            short8v a0 = *(const short8v*)&vs[(ct << 4) + ln][(g << 3)];
            short8v a1 = *(const short8v*)&vs[(ct << 4) + ln][32 + (g << 3)];
            acc_o[ct] = __builtin_amdgcn_mfma_f32_16x16x32_bf16(a0, bp0, acc_o[ct], 0, 0, 0);
            acc_o[ct] = __builtin_amdgcn_mfma_f32_16x16x32_bf16(a1, bp1, acc_o[ct], 0, 0, 0);
        }
    }

    // ---- finalize att = acc / lrun(query=ln), store bf16 att[n][c] in Ps ----
    {
        float l0 = __shfl(lrun[0], bsrc);
        float l1 = __shfl(lrun[1], bsrc);
        float l2 = __shfl(lrun[2], bsrc);
        float l3 = __shfl(lrun[3], bsrc);
        float lsel = (ln & 2) ? ((ln & 1) ? l3 : l2) : ((ln & 1) ? l1 : l0);
        float rl = 1.0f / lsel;
        #pragma unroll
        for (int ct = 0; ct < 4; ++ct)
            #pragma unroll
            for (int r = 0; r < 4; ++r)
                Ps[w][ln][(ct << 4) + (g << 2) + r] = f2bf(acc_o[ct][r] * rl);
    }

    __syncthreads();                           // all waves done with qTs & Ps writes done
    for (int i = tid; i < 1024; i += 256) {
        int r = i >> 4, c4 = (i & 15) << 2;
        float4 wv = *(const float4*)&W2[r * 64 + c4];
        short4v s4 = { f2bf(wv.x), f2bf(wv.y), f2bf(wv.z), f2bf(wv.w) };
        *(short4v*)&qTs[r][c4] = s4;
    }
    __syncthreads();

    // ---- y = W2 * att : D3[o64][n16] ----
    short8v bA0 = *(const short8v*)&Ps[w][ln][(g << 3)];
    short8v bA1 = *(const short8v*)&Ps[w][ln][32 + (g << 3)];
    const int nq = n0 + (w << 4) + ln;
    #pragma unroll
    for (int ot = 0; ot < 4; ++ot) {
        short8v a0 = *(const short8v*)&qTs[(ot << 4) + ln][(g << 3)];
        short8v a1 = *(const short8v*)&qTs[(ot << 4) + ln][32 + (g << 3)];
        floatx4 acc = (floatx4){0.f, 0.f, 0.f, 0.f};
        acc = __builtin_amdgcn_mfma_f32_16x16x32_bf16(a0, bA0, acc, 0, 0, 0);
        acc = __builtin_amdgcn_mfma_f32_16x16x32_bf16(a1, bA1, acc, 0, 0, 0);
        #pragma unroll
        for (int r = 0; r < 4; ++r) {
            int o = (ot << 4) + (g << 2) + r;
            size_t ga = (((size_t)(b << 6) + o) << 12) + nq;
            float yv = acc[r] * bn_inv[o] + bn_bias[o];
            out[ga] = fmaxf(yv, 0.f) + x[ga];
        }
    }
}

// ---------------------------------------------------------------------------
extern "C" void kernel_launch(void* const* d_in, const int* in_sizes, int n_in,
                              void* d_out, int out_size, void* d_ws, size_t ws_size,
                              hipStream_t stream)
{
    const float* x     = (const float*)d_in[0];
    const float* Wk    = (const float*)d_in[1];
    const float* Wq    = (const float*)d_in[2];
    const float* Wv    = (const float*)d_in[3];
    const float* W2    = (const float*)d_in[4];
    const float* gamma = (const float*)d_in[5];
    const float* beta  = (const float*)d_in[6];
    const float* rmean = (const float*)d_in[7];
    const float* rvar  = (const float*)d_in[8];
    float* out = (float*)d_out;

    const size_t plane = (size_t)NB * NTOT * CH;   // 1M elements
    short* kT = (short*)d_ws;
    short* qT = kT + plane;
    short* vv = qT + plane;

    qkv_proj  <<<dim3(256), dim3(256), 0, stream>>>(x, Wk, Wq, Wv, kT, qT, vv);
    fused_attn<<<dim3(256), dim3(256), 0, stream>>>(kT, qT, vv, W2, gamma, beta,
                                                    rmean, rvar, x, out);
}

// Round 4
// 92.436 us; speedup vs baseline: 5.1345x; 1.2573x over previous
//
#include <hip/hip_runtime.h>
#include <math.h>

#define CH   64
#define NTOT 4096
#define NB   4

typedef short  short4v  __attribute__((ext_vector_type(4)));
typedef short  short8v  __attribute__((ext_vector_type(8)));
typedef float  floatx4  __attribute__((ext_vector_type(4)));

static __device__ __forceinline__ short f2bf(float f) {
    union { float f; unsigned int u; } v; v.f = f;
    unsigned int r = v.u + 0x7FFFu + ((v.u >> 16) & 1u);   // RNE
    return (short)(r >> 16);
}

// ---------------------------------------------------------------------------
// Kernel 1: QKV projection (fp32 compute) -> bf16 outputs
//   kT, qT : (B, N, C)  bf16   (pos-major, for MFMA fragment reads)
//   v      : (B, C, N)  bf16
// ---------------------------------------------------------------------------
__global__ __launch_bounds__(256) void qkv_proj(
    const float* __restrict__ x,
    const float* __restrict__ Wk, const float* __restrict__ Wq,
    const float* __restrict__ Wv,
    short* __restrict__ kT, short* __restrict__ qT, short* __restrict__ vg)
{
    __shared__ __align__(16) float xs [64][68];
    __shared__ __align__(16) float wkT[64][68];
    __shared__ __align__(16) float wqT[64][68];
    __shared__ __align__(16) float wvT[64][68];

    const int tid = threadIdx.x;
    const int b  = blockIdx.x >> 6;
    const int n0 = (blockIdx.x & 63) * 64;
    const float* xb = x + (size_t)b * CH * NTOT;

    for (int i = tid; i < 64 * 64; i += 256) {
        int c = i >> 6, n = i & 63;
        xs[c][n] = xb[(size_t)c * NTOT + n0 + n];
    }
    for (int i = tid; i < 64 * 64; i += 256) {
        int o = i >> 6, c = i & 63;
        wkT[c][o] = Wk[i];
        wqT[c][o] = Wq[i];
        wvT[c][o] = Wv[i];
    }
    __syncthreads();

    const int to = tid >> 4, tn = tid & 15;
    const int ob = to * 4, nb = tn * 4;
    float ak[4][4] = {}, aq[4][4] = {}, av[4][4] = {};

    for (int c = 0; c < 64; ++c) {
        float4 xv = *(const float4*)&xs [c][nb];
        float4 k4 = *(const float4*)&wkT[c][ob];
        float4 q4 = *(const float4*)&wqT[c][ob];
        float4 v4 = *(const float4*)&wvT[c][ob];
        float xa[4] = {xv.x, xv.y, xv.z, xv.w};
        float ka[4] = {k4.x, k4.y, k4.z, k4.w};
        float qa[4] = {q4.x, q4.y, q4.z, q4.w};
        float va[4] = {v4.x, v4.y, v4.z, v4.w};
        #pragma unroll
        for (int i = 0; i < 4; ++i)
            #pragma unroll
            for (int j = 0; j < 4; ++j) {
                ak[i][j] += ka[i] * xa[j];
                aq[i][j] += qa[i] * xa[j];
                av[i][j] += va[i] * xa[j];
            }
    }

    #pragma unroll
    for (int j = 0; j < 4; ++j) {
        size_t row = (size_t)(b << 12) + n0 + nb + j;
        short4v kk = { f2bf(ak[0][j]), f2bf(ak[1][j]), f2bf(ak[2][j]), f2bf(ak[3][j]) };
        short4v qq = { f2bf(aq[0][j]), f2bf(aq[1][j]), f2bf(aq[2][j]), f2bf(aq[3][j]) };
        *(short4v*)&kT[row * 64 + ob] = kk;
        *(short4v*)&qT[row * 64 + ob] = qq;
    }
    #pragma unroll
    for (int i = 0; i < 4; ++i) {
        short4v vv = { f2bf(av[i][0]), f2bf(av[i][1]), f2bf(av[i][2]), f2bf(av[i][3]) };
        *(short4v*)&vg[(((size_t)(b << 6) + ob + i) << 12) + n0 + nb] = vv;
    }
}

// ---------------------------------------------------------------------------
// Kernel 2: fused flash attention, K-split x2 in-block.
// 512 threads = 8 waves. Waves 0-3: keys [0,2048); waves 4-7: keys [2048,4096).
// Wave (h, wq) owns queries 16*wq..16*wq+15 over its key half.
// LDS arena (shorts, stride-72 rows):
//   [    0, 4608)  kTs[64][72]          (later: mbuf/lbuf f32; then W2 bf16)
//   [ 4608,13824)  qTs[2][64][72]       (later: xbuf f32 [4][16][68])
//   [13824,23040)  vs [2][64][72]
//   [23040,32256)  Ps [8][16][72]       (half-0 slots reused for final att)
// ---------------------------------------------------------------------------
__global__ __launch_bounds__(512) void fused_attn(
    const short* __restrict__ kT, const short* __restrict__ qT,
    const short* __restrict__ vg,
    const float* __restrict__ W2,
    const float* __restrict__ gamma, const float* __restrict__ beta,
    const float* __restrict__ rmean, const float* __restrict__ rvar,
    const float* __restrict__ x, float* __restrict__ out)
{
    __shared__ __align__(16) short smem[32256];   // 64512 B

    const int tid = threadIdx.x;
    const int w    = tid >> 6;
    const int l    = tid & 63;
    const int g    = l >> 4;
    const int ln   = l & 15;
    const int half = w >> 2;
    const int wq   = w & 3;
    const int bsrc = (ln >> 2) << 4;

    const int bid = blockIdx.x;
    const int xcd = bid & 7, idx = bid >> 3;
    const int b    = xcd >> 1;
    const int nblk = ((xcd & 1) << 5) | idx;
    const int n0   = nblk << 6;

    const short* kTb = kT + ((size_t)(b << 12) + n0) * 64;
    const short* qTb = qT + ((size_t)b << 12) * 64;
    const short* vb  = vg + ((size_t)(b << 6) << 12);

    short* const kTs = smem;
    short* const qH  = smem + 4608  + half * 4608;
    short* const vH  = smem + 13824 + half * 4608;
    short* const PsW = smem + 23040 + w * 1152;

    // stage K tile (queries) once: 512 thr x 8 shorts = 64x64
    {
        int r = tid >> 3, c8 = (tid & 7) << 3;
        *(short8v*)&kTs[r * 72 + c8] = *(const short8v*)&kTb[r * 64 + c8];
    }
    __syncthreads();

    short8v aS0 = *(const short8v*)&kTs[((wq << 4) + ln) * 72 + (g << 3)];
    short8v aS1 = *(const short8v*)&kTs[((wq << 4) + ln) * 72 + 32 + (g << 3)];

    float mrun[4] = {-1e30f, -1e30f, -1e30f, -1e30f};
    float lrun[4] = {0.f, 0.f, 0.f, 0.f};
    floatx4 acc_o[4];
    #pragma unroll
    for (int ct = 0; ct < 4; ++ct) acc_o[ct] = (floatx4){0.f, 0.f, 0.f, 0.f};

    const int m0h = half << 11;               // key base of this half
    const int i0 = tid & 255, i1 = (tid & 255) + 256;

    short8v pf[4];
    pf[0] = *(const short8v*)&qTb[(size_t)(m0h + (i0 >> 3)) * 64 + ((i0 & 7) << 3)];
    pf[1] = *(const short8v*)&qTb[(size_t)(m0h + (i1 >> 3)) * 64 + ((i1 & 7) << 3)];
    pf[2] = *(const short8v*)&vb[(size_t)(i0 >> 3) * 4096 + m0h + ((i0 & 7) << 3)];
    pf[3] = *(const short8v*)&vb[(size_t)(i1 >> 3) * 4096 + m0h + ((i1 & 7) << 3)];

    for (int t = 0; t < 32; ++t) {
        __syncthreads();                       // previous tile's readers done
        *(short8v*)&qH[(i0 >> 3) * 72 + ((i0 & 7) << 3)] = pf[0];
        *(short8v*)&qH[(i1 >> 3) * 72 + ((i1 & 7) << 3)] = pf[1];
        *(short8v*)&vH[(i0 >> 3) * 72 + ((i0 & 7) << 3)] = pf[2];
        *(short8v*)&vH[(i1 >> 3) * 72 + ((i1 & 7) << 3)] = pf[3];
        __syncthreads();                       // tile ready
        if (t < 31) {
            int m1 = m0h + ((t + 1) << 6);
            pf[0] = *(const short8v*)&qTb[(size_t)(m1 + (i0 >> 3)) * 64 + ((i0 & 7) << 3)];
            pf[1] = *(const short8v*)&qTb[(size_t)(m1 + (i1 >> 3)) * 64 + ((i1 & 7) << 3)];
            pf[2] = *(const short8v*)&vb[(size_t)(i0 >> 3) * 4096 + m1 + ((i0 & 7) << 3)];
            pf[3] = *(const short8v*)&vb[(size_t)(i1 >> 3) * 4096 + m1 + ((i1 & 7) << 3)];
        }

        // ---- S tile: D[n16][m64] = sum_c kT[n][c] * q[c][m] ----
        floatx4 sacc[4];
        #pragma unroll
        for (int mt = 0; mt < 4; ++mt) {
            short8v b0 = *(const short8v*)&qH[((mt << 4) + ln) * 72 + (g << 3)];
            short8v b1 = *(const short8v*)&qH[((mt << 4) + ln) * 72 + 32 + (g << 3)];
            floatx4 acc = (floatx4){0.f, 0.f, 0.f, 0.f};
            acc = __builtin_amdgcn_mfma_f32_16x16x32_bf16(aS0, b0, acc, 0, 0, 0);
            acc = __builtin_amdgcn_mfma_f32_16x16x32_bf16(aS1, b1, acc, 0, 0, 0);
            sacc[mt] = acc;
        }

        // ---- online softmax over m ----
        float fs[4];
        #pragma unroll
        for (int r = 0; r < 4; ++r) {
            float mx = fmaxf(fmaxf(sacc[0][r], sacc[1][r]), fmaxf(sacc[2][r], sacc[3][r]));
            mx = fmaxf(mx, __shfl_xor(mx, 1));
            mx = fmaxf(mx, __shfl_xor(mx, 2));
            mx = fmaxf(mx, __shfl_xor(mx, 4));
            mx = fmaxf(mx, __shfl_xor(mx, 8));
            float mnew = fmaxf(mrun[r], mx);
            fs[r] = __expf(mrun[r] - mnew);
            mrun[r] = mnew;
            float s = 0.f;
            #pragma unroll
            for (int mt = 0; mt < 4; ++mt) {
                float p = __expf(sacc[mt][r] - mnew);
                s += p;
                PsW[((g << 2) + r) * 72 + (mt << 4) + ln] = f2bf(p);
            }
            s += __shfl_xor(s, 1);
            s += __shfl_xor(s, 2);
            s += __shfl_xor(s, 4);
            s += __shfl_xor(s, 8);
            lrun[r] = lrun[r] * fs[r] + s;
        }

        // broadcast fs(query=ln) via register shuffles
        {
            float f0 = __shfl(fs[0], bsrc);
            float f1 = __shfl(fs[1], bsrc);
            float f2 = __shfl(fs[2], bsrc);
            float f3 = __shfl(fs[3], bsrc);
            float fsn = (ln & 2) ? ((ln & 1) ? f3 : f2) : ((ln & 1) ? f1 : f0);
            #pragma unroll
            for (int ct = 0; ct < 4; ++ct) {
                acc_o[ct][0] *= fsn; acc_o[ct][1] *= fsn;
                acc_o[ct][2] *= fsn; acc_o[ct][3] *= fsn;
            }
        }

        __syncthreads();   // Ps writes ordered before PV fragment reads

        // ---- PV: D2[c64][n16] += v[c][m] * P^T[m][n] ----
        short8v bp0 = *(const short8v*)&PsW[ln * 72 + (g << 3)];
        short8v bp1 = *(const short8v*)&PsW[ln * 72 + 32 + (g << 3)];
        #pragma unroll
        for (int ct = 0; ct < 4; ++ct) {
            short8v a0 = *(const short8v*)&vH[((ct << 4) + ln) * 72 + (g << 3)];
            short8v a1 = *(const short8v*)&vH[((ct << 4) + ln) * 72 + 32 + (g << 3)];
            acc_o[ct] = __builtin_amdgcn_mfma_f32_16x16x32_bf16(a0, bp0, acc_o[ct], 0, 0, 0);
            acc_o[ct] = __builtin_amdgcn_mfma_f32_16x16x32_bf16(a1, bp1, acc_o[ct], 0, 0, 0);
        }
    }

    // ================= merge the two key-half partials =================
    float* mb = (float*)smem;   // m[2][4][16] @0..127, l[2][4][16] @128..255
    if (ln == 0) {
        #pragma unroll
        for (int r = 0; r < 4; ++r) {
            mb[(((half << 2) | wq) << 4) + (g << 2) + r]       = mrun[r];
            mb[128 + (((half << 2) | wq) << 4) + (g << 2) + r] = lrun[r];
        }
    }
    __syncthreads();

    float m0v = mb[(wq << 4) + ln];
    float m1v = mb[64 + (wq << 4) + ln];
    float l0v = mb[128 + (wq << 4) + ln];
    float l1v = mb[192 + (wq << 4) + ln];
    float mm = fmaxf(m0v, m1v);
    float s0 = __expf(m0v - mm), s1 = __expf(m1v - mm);

    float* xbuf = (float*)(smem + 4608);   // [4][16][68]
    if (half == 1) {
        #pragma unroll
        for (int ct = 0; ct < 4; ++ct) {
            float4 w4 = make_float4(acc_o[ct][0] * s1, acc_o[ct][1] * s1,
                                    acc_o[ct][2] * s1, acc_o[ct][3] * s1);
            *(float4*)&xbuf[((wq << 4) + ln) * 68 + (ct << 4) + (g << 2)] = w4;
        }
    }
    __syncthreads();
    if (half == 0) {
        float linv = 1.0f / (l0v * s0 + l1v * s1);
        #pragma unroll
        for (int ct = 0; ct < 4; ++ct) {
            float4 x1 = *(const float4*)&xbuf[((wq << 4) + ln) * 68 + (ct << 4) + (g << 2)];
            float xa[4] = {x1.x, x1.y, x1.z, x1.w};
            #pragma unroll
            for (int r = 0; r < 4; ++r) {
                float att = (acc_o[ct][r] * s0 + xa[r]) * linv;
                PsW[ln * 72 + (ct << 4) + (g << 2) + r] = f2bf(att);
            }
        }
    }
    __syncthreads();

    // stage W2 bf16 [o][c] (stride 72) at smem[0]
    for (int i = tid; i < 1024; i += 512) {
        int r = i >> 4, c4 = (i & 15) << 2;
        float4 wv = *(const float4*)&W2[(r << 6) + c4];
        short4v s4 = { f2bf(wv.x), f2bf(wv.y), f2bf(wv.z), f2bf(wv.w) };
        *(short4v*)&smem[r * 72 + c4] = s4;
    }
    __syncthreads();

    // ---- y = W2 * att + BN + ReLU + residual ----
    const int sq  = w & 3;                 // source query-wave
    const int ob2 = (w >> 2) << 1;         // output-tile pair
    const short* PsQ = smem + 23040 + sq * 1152;
    short8v bA0 = *(const short8v*)&PsQ[ln * 72 + (g << 3)];
    short8v bA1 = *(const short8v*)&PsQ[ln * 72 + 32 + (g << 3)];
    const int nq = n0 + (sq << 4) + ln;
    #pragma unroll
    for (int oi = 0; oi < 2; ++oi) {
        int ot = ob2 + oi;
        short8v a0 = *(const short8v*)&smem[((ot << 4) + ln) * 72 + (g << 3)];
        short8v a1 = *(const short8v*)&smem[((ot << 4) + ln) * 72 + 32 + (g << 3)];
        floatx4 acc = (floatx4){0.f, 0.f, 0.f, 0.f};
        acc = __builtin_amdgcn_mfma_f32_16x16x32_bf16(a0, bA0, acc, 0, 0, 0);
        acc = __builtin_amdgcn_mfma_f32_16x16x32_bf16(a1, bA1, acc, 0, 0, 0);
        int o0 = (ot << 4) + (g << 2);
        float4 gm = *(const float4*)&gamma[o0];
        float4 bt = *(const float4*)&beta [o0];
        float4 rm = *(const float4*)&rmean[o0];
        float4 rv = *(const float4*)&rvar [o0];
        float gma[4] = {gm.x, gm.y, gm.z, gm.w};
        float bta[4] = {bt.x, bt.y, bt.z, bt.w};
        float rma[4] = {rm.x, rm.y, rm.z, rm.w};
        float rva[4] = {rv.x, rv.y, rv.z, rv.w};
        #pragma unroll
        for (int r = 0; r < 4; ++r) {
            float inv  = gma[r] * rsqrtf(rva[r] + 1e-5f);
            float bias = bta[r] - rma[r] * inv;
            size_t ga = (((size_t)(b << 6) + o0 + r) << 12) + nq;
            out[ga] = fmaxf(acc[r] * inv + bias, 0.f) + x[ga];
        }
    }
}

// ---------------------------------------------------------------------------
extern "C" void kernel_launch(void* const* d_in, const int* in_sizes, int n_in,
                              void* d_out, int out_size, void* d_ws, size_t ws_size,
                              hipStream_t stream)
{
    const float* x     = (const float*)d_in[0];
    const float* Wk    = (const float*)d_in[1];
    const float* Wq    = (const float*)d_in[2];
    const float* Wv    = (const float*)d_in[3];
    const float* W2    = (const float*)d_in[4];
    const float* gamma = (const float*)d_in[5];
    const float* beta  = (const float*)d_in[6];
    const float* rmean = (const float*)d_in[7];
    const float* rvar  = (const float*)d_in[8];
    float* out = (float*)d_out;

    const size_t plane = (size_t)NB * NTOT * CH;   // 1M elements
    short* kT = (short*)d_ws;
    short* qT = kT + plane;
    short* vv = qT + plane;

    qkv_proj  <<<dim3(256), dim3(256), 0, stream>>>(x, Wk, Wq, Wv, kT, qT, vv);
    fused_attn<<<dim3(256), dim3(512), 0, stream>>>(kT, qT, vv, W2, gamma, beta,
                                                    rmean, rvar, x, out);
}

// Round 5
// 60.382 us; speedup vs baseline: 7.8603x; 1.5309x over previous
//
#include <hip/hip_runtime.h>
#include <math.h>

#define CH   64
#define NTOT 4096
#define NB   4

typedef short  short4v  __attribute__((ext_vector_type(4)));
typedef short  short8v  __attribute__((ext_vector_type(8)));
typedef float  floatx4  __attribute__((ext_vector_type(4)));

static __device__ __forceinline__ short f2bf(float f) {
    union { float f; unsigned int u; } v; v.f = f;
    unsigned int r = v.u + 0x7FFFu + ((v.u >> 16) & 1u);   // RNE
    return (short)(r >> 16);
}

// ---------------------------------------------------------------------------
// Kernel 1: QKV projection (fp32 compute) -> bf16 outputs
//   kT, qT : (B, N, C)  bf16   (pos-major, for MFMA fragment reads)
//   v      : (B, C, N)  bf16
// ---------------------------------------------------------------------------
__global__ __launch_bounds__(256) void qkv_proj(
    const float* __restrict__ x,
    const float* __restrict__ Wk, const float* __restrict__ Wq,
    const float* __restrict__ Wv,
    short* __restrict__ kT, short* __restrict__ qT, short* __restrict__ vg)
{
    __shared__ __align__(16) float xs [64][68];
    __shared__ __align__(16) float wkT[64][68];
    __shared__ __align__(16) float wqT[64][68];
    __shared__ __align__(16) float wvT[64][68];

    const int tid = threadIdx.x;
    const int b  = blockIdx.x >> 6;
    const int n0 = (blockIdx.x & 63) * 64;
    const float* xb = x + (size_t)b * CH * NTOT;

    for (int i = tid; i < 64 * 64; i += 256) {
        int c = i >> 6, n = i & 63;
        xs[c][n] = xb[(size_t)c * NTOT + n0 + n];
    }
    for (int i = tid; i < 64 * 64; i += 256) {
        int o = i >> 6, c = i & 63;
        wkT[c][o] = Wk[i];
        wqT[c][o] = Wq[i];
        wvT[c][o] = Wv[i];
    }
    __syncthreads();

    const int to = tid >> 4, tn = tid & 15;
    const int ob = to * 4, nb = tn * 4;
    float ak[4][4] = {}, aq[4][4] = {}, av[4][4] = {};

    for (int c = 0; c < 64; ++c) {
        float4 xv = *(const float4*)&xs [c][nb];
        float4 k4 = *(const float4*)&wkT[c][ob];
        float4 q4 = *(const float4*)&wqT[c][ob];
        float4 v4 = *(const float4*)&wvT[c][ob];
        float xa[4] = {xv.x, xv.y, xv.z, xv.w};
        float ka[4] = {k4.x, k4.y, k4.z, k4.w};
        float qa[4] = {q4.x, q4.y, q4.z, q4.w};
        float va[4] = {v4.x, v4.y, v4.z, v4.w};
        #pragma unroll
        for (int i = 0; i < 4; ++i)
            #pragma unroll
            for (int j = 0; j < 4; ++j) {
                ak[i][j] += ka[i] * xa[j];
                aq[i][j] += qa[i] * xa[j];
                av[i][j] += va[i] * xa[j];
            }
    }

    #pragma unroll
    for (int j = 0; j < 4; ++j) {
        size_t row = (size_t)(b << 12) + n0 + nb + j;
        short4v kk = { f2bf(ak[0][j]), f2bf(ak[1][j]), f2bf(ak[2][j]), f2bf(ak[3][j]) };
        short4v qq = { f2bf(aq[0][j]), f2bf(aq[1][j]), f2bf(aq[2][j]), f2bf(aq[3][j]) };
        *(short4v*)&kT[row * 64 + ob] = kk;
        *(short4v*)&qT[row * 64 + ob] = qq;
    }
    #pragma unroll
    for (int i = 0; i < 4; ++i) {
        short4v vv = { f2bf(av[i][0]), f2bf(av[i][1]), f2bf(av[i][2]), f2bf(av[i][3]) };
        *(short4v*)&vg[(((size_t)(b << 6) + ob + i) << 12) + n0 + nb] = vv;
    }
}

// ---------------------------------------------------------------------------
// Kernel 2: fused flash attention, K-split x2 in-block, S^T layout.
// 512 threads = 8 waves. Waves 0-3: keys [0,2048); waves 4-7: keys [2048,4096).
// Wave (h, wq) owns queries 16*wq..16*wq+15 over its key half.
// S^T MFMA: lane (g,ln) holds S[m = 16mt+4g+r][n = ln] -> softmax of one
// query lives in one lane (plus 2 shfl_xor across the 4 g-lanes).
// ---------------------------------------------------------------------------
__global__ __launch_bounds__(512) void fused_attn(
    const short* __restrict__ kT, const short* __restrict__ qT,
    const short* __restrict__ vg,
    const float* __restrict__ W2,
    const float* __restrict__ gamma, const float* __restrict__ beta,
    const float* __restrict__ rmean, const float* __restrict__ rvar,
    const float* __restrict__ x, float* __restrict__ out)
{
    __shared__ __align__(16) short smem[32256];   // 64512 B

    const int tid = threadIdx.x;
    const int w    = tid >> 6;
    const int l    = tid & 63;
    const int g    = l >> 4;
    const int ln   = l & 15;
    const int half = w >> 2;
    const int wq   = w & 3;

    const int bid = blockIdx.x;
    const int xcd = bid & 7, idx = bid >> 3;
    const int b    = xcd >> 1;
    const int nblk = ((xcd & 1) << 5) | idx;
    const int n0   = nblk << 6;

    const short* kTb = kT + ((size_t)(b << 12) + n0) * 64;
    const short* qTb = qT + ((size_t)b << 12) * 64;
    const short* vb  = vg + ((size_t)(b << 6) << 12);

    short* const kTs = smem;
    short* const qH  = smem + 4608  + half * 4608;
    short* const vH  = smem + 13824 + half * 4608;
    short* const PsW = smem + 23040 + w * 1152;

    // stage K tile (this block's 64 queries) once
    {
        int r = tid >> 3, c8 = (tid & 7) << 3;
        *(short8v*)&kTs[r * 72 + c8] = *(const short8v*)&kTb[r * 64 + c8];
    }
    __syncthreads();

    // queries as B-fragment: B[k=c][col=n(ln)] = kT[(wq<<4)+ln][c]
    short8v bS0 = *(const short8v*)&kTs[((wq << 4) + ln) * 72 + (g << 3)];
    short8v bS1 = *(const short8v*)&kTs[((wq << 4) + ln) * 72 + 32 + (g << 3)];

    float mrun = -1e30f;
    float lrun = 0.f;
    floatx4 acc_o[4];
    #pragma unroll
    for (int ct = 0; ct < 4; ++ct) acc_o[ct] = (floatx4){0.f, 0.f, 0.f, 0.f};

    const int m0h = half << 11;               // key base of this half
    const int i0 = tid & 255, i1 = (tid & 255) + 256;

    short8v pf[4];
    pf[0] = *(const short8v*)&qTb[(size_t)(m0h + (i0 >> 3)) * 64 + ((i0 & 7) << 3)];
    pf[1] = *(const short8v*)&qTb[(size_t)(m0h + (i1 >> 3)) * 64 + ((i1 & 7) << 3)];
    pf[2] = *(const short8v*)&vb[(size_t)(i0 >> 3) * 4096 + m0h + ((i0 & 7) << 3)];
    pf[3] = *(const short8v*)&vb[(size_t)(i1 >> 3) * 4096 + m0h + ((i1 & 7) << 3)];

    for (int t = 0; t < 32; ++t) {
        __syncthreads();                       // previous tile's readers done
        *(short8v*)&qH[(i0 >> 3) * 72 + ((i0 & 7) << 3)] = pf[0];
        *(short8v*)&qH[(i1 >> 3) * 72 + ((i1 & 7) << 3)] = pf[1];
        *(short8v*)&vH[(i0 >> 3) * 72 + ((i0 & 7) << 3)] = pf[2];
        *(short8v*)&vH[(i1 >> 3) * 72 + ((i1 & 7) << 3)] = pf[3];
        __syncthreads();                       // tile ready
        if (t < 31) {
            int m1 = m0h + ((t + 1) << 6);
            pf[0] = *(const short8v*)&qTb[(size_t)(m1 + (i0 >> 3)) * 64 + ((i0 & 7) << 3)];
            pf[1] = *(const short8v*)&qTb[(size_t)(m1 + (i1 >> 3)) * 64 + ((i1 & 7) << 3)];
            pf[2] = *(const short8v*)&vb[(size_t)(i0 >> 3) * 4096 + m1 + ((i0 & 7) << 3)];
            pf[3] = *(const short8v*)&vb[(size_t)(i1 >> 3) * 4096 + m1 + ((i1 & 7) << 3)];
        }

        // ---- S^T tile: D[m16][n16] per mt; A = keys (qH rows), B = queries ----
        floatx4 sacc[4];
        #pragma unroll
        for (int mt = 0; mt < 4; ++mt) {
            short8v a0 = *(const short8v*)&qH[((mt << 4) + ln) * 72 + (g << 3)];
            short8v a1 = *(const short8v*)&qH[((mt << 4) + ln) * 72 + 32 + (g << 3)];
            floatx4 acc = (floatx4){0.f, 0.f, 0.f, 0.f};
            acc = __builtin_amdgcn_mfma_f32_16x16x32_bf16(a0, bS0, acc, 0, 0, 0);
            acc = __builtin_amdgcn_mfma_f32_16x16x32_bf16(a1, bS1, acc, 0, 0, 0);
            sacc[mt] = acc;
        }

        // ---- online softmax: all 16 m-values for query n=ln are in-lane ----
        float mx = sacc[0][0];
        #pragma unroll
        for (int mt = 0; mt < 4; ++mt)
            #pragma unroll
            for (int r = 0; r < 4; ++r) mx = fmaxf(mx, sacc[mt][r]);
        mx = fmaxf(mx, __shfl_xor(mx, 16));
        mx = fmaxf(mx, __shfl_xor(mx, 32));

        float mnew = fmaxf(mrun, mx);
        float fs = __expf(mrun - mnew);
        mrun = mnew;

        float s = 0.f;
        #pragma unroll
        for (int mt = 0; mt < 4; ++mt) {
            float p0 = __expf(sacc[mt][0] - mnew);
            float p1 = __expf(sacc[mt][1] - mnew);
            float p2 = __expf(sacc[mt][2] - mnew);
            float p3 = __expf(sacc[mt][3] - mnew);
            s += (p0 + p1) + (p2 + p3);
            short4v p4 = { f2bf(p0), f2bf(p1), f2bf(p2), f2bf(p3) };
            *(short4v*)&PsW[ln * 72 + (mt << 4) + (g << 2)] = p4;
        }
        s += __shfl_xor(s, 16);
        s += __shfl_xor(s, 32);
        lrun = lrun * fs + s;

        // rescale accumulator (acc column n == ln: same lane, no broadcast)
        #pragma unroll
        for (int ct = 0; ct < 4; ++ct) {
            acc_o[ct][0] *= fs; acc_o[ct][1] *= fs;
            acc_o[ct][2] *= fs; acc_o[ct][3] *= fs;
        }

        // ---- PV: D2[c64][n16] += v[c][m] * P^T[m][n]  (intra-wave LDS dep) ----
        short8v bp0 = *(const short8v*)&PsW[ln * 72 + (g << 3)];
        short8v bp1 = *(const short8v*)&PsW[ln * 72 + 32 + (g << 3)];
        #pragma unroll
        for (int ct = 0; ct < 4; ++ct) {
            short8v a0 = *(const short8v*)&vH[((ct << 4) + ln) * 72 + (g << 3)];
            short8v a1 = *(const short8v*)&vH[((ct << 4) + ln) * 72 + 32 + (g << 3)];
            acc_o[ct] = __builtin_amdgcn_mfma_f32_16x16x32_bf16(a0, bp0, acc_o[ct], 0, 0, 0);
            acc_o[ct] = __builtin_amdgcn_mfma_f32_16x16x32_bf16(a1, bp1, acc_o[ct], 0, 0, 0);
        }
    }

    // ================= merge the two key-half partials =================
    float* mb = (float*)smem;   // m[2][4][16] @0..127, l[2][4][16] @128..255
    if (g == 0) {
        mb[(((half << 2) | wq) << 4) + ln]       = mrun;
        mb[128 + (((half << 2) | wq) << 4) + ln] = lrun;
    }
    __syncthreads();

    float m0v = mb[(wq << 4) + ln];
    float m1v = mb[64 + (wq << 4) + ln];
    float l0v = mb[128 + (wq << 4) + ln];
    float l1v = mb[192 + (wq << 4) + ln];
    float mm = fmaxf(m0v, m1v);
    float s0 = __expf(m0v - mm), s1 = __expf(m1v - mm);

    float* xbuf = (float*)(smem + 4608);   // [64 n][68 c] f32
    if (half == 1) {
        #pragma unroll
        for (int ct = 0; ct < 4; ++ct) {
            float4 w4 = make_float4(acc_o[ct][0] * s1, acc_o[ct][1] * s1,
                                    acc_o[ct][2] * s1, acc_o[ct][3] * s1);
            *(float4*)&xbuf[((wq << 4) + ln) * 68 + (ct << 4) + (g << 2)] = w4;
        }
    }
    __syncthreads();
    if (half == 0) {
        float linv = 1.0f / (l0v * s0 + l1v * s1);
        #pragma unroll
        for (int ct = 0; ct < 4; ++ct) {
            float4 x1 = *(const float4*)&xbuf[((wq << 4) + ln) * 68 + (ct << 4) + (g << 2)];
            float xa[4] = {x1.x, x1.y, x1.z, x1.w};
            short4v a4 = { f2bf((acc_o[ct][0] * s0 + xa[0]) * linv),
                           f2bf((acc_o[ct][1] * s0 + xa[1]) * linv),
                           f2bf((acc_o[ct][2] * s0 + xa[2]) * linv),
                           f2bf((acc_o[ct][3] * s0 + xa[3]) * linv) };
            *(short4v*)&PsW[ln * 72 + (ct << 4) + (g << 2)] = a4;
        }
    }
    __syncthreads();

    // stage W2 bf16 [o][c] (stride 72) at smem[0]
    for (int i = tid; i < 1024; i += 512) {
        int r = i >> 4, c4 = (i & 15) << 2;
        float4 wv = *(const float4*)&W2[(r << 6) + c4];
        short4v s4 = { f2bf(wv.x), f2bf(wv.y), f2bf(wv.z), f2bf(wv.w) };
        *(short4v*)&smem[r * 72 + c4] = s4;
    }
    __syncthreads();

    // ---- y = W2 * att + BN + ReLU + residual ----
    const int sq  = w & 3;                 // source query-wave
    const int ob2 = (w >> 2) << 1;         // output-tile pair
    const short* PsQ = smem + 23040 + sq * 1152;
    short8v bA0 = *(const short8v*)&PsQ[ln * 72 + (g << 3)];
    short8v bA1 = *(const short8v*)&PsQ[ln * 72 + 32 + (g << 3)];
    const int nq = n0 + (sq << 4) + ln;
    #pragma unroll
    for (int oi = 0; oi < 2; ++oi) {
        int ot = ob2 + oi;
        short8v a0 = *(const short8v*)&smem[((ot << 4) + ln) * 72 + (g << 3)];
        short8v a1 = *(const short8v*)&smem[((ot << 4) + ln) * 72 + 32 + (g << 3)];
        floatx4 acc = (floatx4){0.f, 0.f, 0.f, 0.f};
        acc = __builtin_amdgcn_mfma_f32_16x16x32_bf16(a0, bA0, acc, 0, 0, 0);
        acc = __builtin_amdgcn_mfma_f32_16x16x32_bf16(a1, bA1, acc, 0, 0, 0);
        int o0 = (ot << 4) + (g << 2);
        float4 gm = *(const float4*)&gamma[o0];
        float4 bt = *(const float4*)&beta [o0];
        float4 rm = *(const float4*)&rmean[o0];
        float4 rv = *(const float4*)&rvar [o0];
        float gma[4] = {gm.x, gm.y, gm.z, gm.w};
        float bta[4] = {bt.x, bt.y, bt.z, bt.w};
        float rma[4] = {rm.x, rm.y, rm.z, rm.w};
        float rva[4] = {rv.x, rv.y, rv.z, rv.w};
        #pragma unroll
        for (int r = 0; r < 4; ++r) {
            float inv  = gma[r] * rsqrtf(rva[r] + 1e-5f);
            float bias = bta[r] - rma[r] * inv;
            size_t ga = (((size_t)(b << 6) + o0 + r) << 12) + nq;
            out[ga] = fmaxf(acc[r] * inv + bias, 0.f) + x[ga];
        }
    }
}

// ---------------------------------------------------------------------------
extern "C" void kernel_launch(void* const* d_in, const int* in_sizes, int n_in,
                              void* d_out, int out_size, void* d_ws, size_t ws_size,
                              hipStream_t stream)
{
    const float* x     = (const float*)d_in[0];
    const float* Wk    = (const float*)d_in[1];
    const float* Wq    = (const float*)d_in[2];
    const float* Wv    = (const float*)d_in[3];
    const float* W2    = (const float*)d_in[4];
    const float* gamma = (const float*)d_in[5];
    const float* beta  = (const float*)d_in[6];
    const float* rmean = (const float*)d_in[7];
    const float* rvar  = (const float*)d_in[8];
    float* out = (float*)d_out;

    const size_t plane = (size_t)NB * NTOT * CH;   // 1M elements
    short* kT = (short*)d_ws;
    short* qT = kT + plane;
    short* vv = qT + plane;

    qkv_proj  <<<dim3(256), dim3(256), 0, stream>>>(x, Wk, Wq, Wv, kT, qT, vv);
    fused_attn<<<dim3(256), dim3(512), 0, stream>>>(kT, qT, vv, W2, gamma, beta,
                                                    rmean, rvar, x, out);
}